// Round 9
// baseline (350.453 us; speedup 1.0000x reference)
//
#include <hip/hip_runtime.h>
#include <stdint.h>

#define HASH_BUCKETS 1000
#define EMB_DIM 16
#define HDIM 32
#define G4 128   // 4*HDIM
#define TSTEPS 512
#define BATCH 4096

typedef short v8s __attribute__((ext_vector_type(8)));   // 8 bf16 (4 VGPRs)
typedef float v4f __attribute__((ext_vector_type(4)));   // MFMA acc

__device__ __forceinline__ float frcp(float x) {
    float r; asm("v_rcp_f32 %0, %1" : "=v"(r) : "v"(x)); return r;
}
__device__ __forceinline__ float fexp2(float x) {
    float r; asm("v_exp_f32 %0, %1" : "=v"(r) : "v"(x)); return r;
}
// f32 -> bf16 (RNE), returns bits in low 16
__device__ __forceinline__ uint32_t bf16rne(float x) {
    uint32_t u = __float_as_uint(x);
    return (u + 0x7FFFu + ((u >> 16) & 1u)) >> 16;
}

// ---------------------------------------------------------------------------
// Kernel 1: fold embedding through input projection (unchanged layout):
// P2[bucket][h][g] = sum_e emb[bucket][e] * kernel[e][g*32 + h]
// ---------------------------------------------------------------------------
__global__ void precompute_P2_kernel(const float* __restrict__ emb,
                                     const float* __restrict__ kern,
                                     float* __restrict__ P2) {
    int idx = blockIdx.x * blockDim.x + threadIdx.x;
    if (idx >= HASH_BUCKETS * G4) return;
    int row = idx >> 7;
    int c2  = idx & 127;
    int h = c2 >> 2;
    int g = c2 & 3;
    float acc = 0.f;
#pragma unroll
    for (int e = 0; e < EMB_DIM; ++e)
        acc = fmaf(emb[row * EMB_DIM + e], kern[e * G4 + g * 32 + h], acc);
    P2[idx] = acc;
}

// ---------------------------------------------------------------------------
// Kernel 2: MFMA LSTM. Block = 512 threads = 8 waves = 16 batch elements.
// Wave w computes z^T chunk [16 rows][16 batch] with ONE 16x16x32 bf16 MFMA
// (x3 for split-bf16 precision), rows permuted as m = t*4 + g so that lane
// (quad,col) gets (i,f,c,o) of (h_idx = 4w+quad, batch = col) in its 4 acc
// regs (C/D: col=lane&15, row=quad*4+reg). A = R^T chunk (static, split
// bf16 hi/lo in registers). B = h (split bf16, packed hi|lo per dword in
// LDS). xz seeds the MFMA C operand for free. h ping-pongs through LDS with
// one __syncthreads per step. k-element-order inside fragments is
// self-canceling (same convention used for A and B).
// ---------------------------------------------------------------------------
__global__ __launch_bounds__(512)
void lstm_head_kernel(const int* __restrict__ ids,
                      const float* __restrict__ P2,   // [1000][32][4]
                      const float* __restrict__ R,    // rec_kernel [32][128]
                      const float* __restrict__ w1,   // [32][32]
                      const float* __restrict__ b1,   // [32]
                      const float* __restrict__ w2,   // [32]
                      const float* __restrict__ b2,   // [1]
                      float* __restrict__ out) {
    // packed h: dword = (hi_bf16 << 16) | lo_bf16 ; stride 36 dwords:
    // writes (4col+4w+quad)%32 -> 2-way max; b128 reads hit all 32 banks.
    __shared__ __align__(16) uint32_t hbuf[2][16][36];
    __shared__ float hfin[16][33];

    const int tid  = threadIdx.x;
    const int w    = tid >> 6;        // wave 0..7
    const int lane = tid & 63;
    const int col  = lane & 15;       // batch within group / A row m
    const int quad = lane >> 4;       // 0..3
    const int bb   = blockIdx.x * 16;

    // ---- A fragments: R^T rows m = t*4+g -> gatecol = g*32 + 4w + t ----
    union V8 { uint32_t u[4]; v8s v; };
    V8 Ahi, Alo;
    {
        int tt = col >> 2, g = col & 3;
        int gcol = g * 32 + 4 * w + tt;
#pragma unroll
        for (int r = 0; r < 4; ++r) {
            uint32_t hp[2], lp[2];
#pragma unroll
            for (int e = 0; e < 2; ++e) {
                int k = quad * 8 + 2 * r + e;
                float x = R[k * G4 + gcol];
                uint32_t hb = bf16rne(x);
                float lo = x - __uint_as_float(hb << 16);
                hp[e] = hb;
                lp[e] = bf16rne(lo);
            }
            Ahi.u[r] = hp[0] | (hp[1] << 16);
            Alo.u[r] = lp[0] | (lp[1] << 16);
        }
    }

    // zero both h buffers (h0 = 0)
    for (int i = tid; i < 2 * 16 * 36; i += 512)
        ((uint32_t*)hbuf)[i] = 0u;

    // ---- id / xz pipeline (per lane: batch = col) ----
    const int* __restrict__ idrow = ids + (size_t)(bb + col) * TSTEPS;
    const int xzoff = (4 * w + quad) * 4;
    int idn = idrow[0];
    float4 xz = *(const float4*)(P2 + (size_t)idn * G4 + xzoff);
    idn = idrow[1];

    float c = 0.f, hval = 0.f;
    int p = 0;
    const float NL2E  = -1.4426950408889634f;
    const float P2L2E =  2.8853900817779268f;

    __syncthreads();

    for (int t = 0; t < TSTEPS; ++t) {
        // B fragment: 8 packed dwords (k = quad*8 + e) for batch=col
        const uint32_t* hrow = &hbuf[p][col][0] + 8 * quad;
        uint4 dA = *(const uint4*)hrow;
        uint4 dB = *(const uint4*)(hrow + 4);

        // prefetch next xz / next-next id
        float4 xzn = *(const float4*)(P2 + (size_t)idn * G4 + xzoff);
        int idnn = idrow[(t + 2 < TSTEPS) ? (t + 2) : (TSTEPS - 1)];

        V8 Bhi, Blo;
        Bhi.u[0] = __builtin_amdgcn_perm(dA.y, dA.x, 0x07060302u);
        Bhi.u[1] = __builtin_amdgcn_perm(dA.w, dA.z, 0x07060302u);
        Bhi.u[2] = __builtin_amdgcn_perm(dB.y, dB.x, 0x07060302u);
        Bhi.u[3] = __builtin_amdgcn_perm(dB.w, dB.z, 0x07060302u);
        Blo.u[0] = __builtin_amdgcn_perm(dA.y, dA.x, 0x05040100u);
        Blo.u[1] = __builtin_amdgcn_perm(dA.w, dA.z, 0x05040100u);
        Blo.u[2] = __builtin_amdgcn_perm(dB.y, dB.x, 0x05040100u);
        Blo.u[3] = __builtin_amdgcn_perm(dB.w, dB.z, 0x05040100u);

        // z = Ahi*Bhi + Ahi*Blo + Alo*Bhi + xz   (lo*lo dropped, ~2^-18)
        v4f acc = { xz.x, xz.y, xz.z, xz.w };
        acc = __builtin_amdgcn_mfma_f32_16x16x32_bf16(Alo.v, Bhi.v, acc, 0, 0, 0);
        acc = __builtin_amdgcn_mfma_f32_16x16x32_bf16(Ahi.v, Blo.v, acc, 0, 0, 0);
        acc = __builtin_amdgcn_mfma_f32_16x16x32_bf16(Ahi.v, Bhi.v, acc, 0, 0, 0);

        float zi = acc[0], zf = acc[1], zc = acc[2], zo = acc[3];

        // gates: exp2-based, args clamped <=31, grouped reciprocal
        float ai = fminf(31.f, NL2E  * zi);
        float af = fminf(31.f, NL2E  * zf);
        float ac = fminf(31.f, P2L2E * zc);
        float ao = fminf(31.f, NL2E  * zo);
        float di = 1.f + fexp2(ai);
        float df = 1.f + fexp2(af);
        float dc = 1.f + fexp2(ac);
        float dq = 1.f + fexp2(ao);
        float Pp = di * df;
        float Qq = dc * dq;
        float rr = frcp(Pp * Qq);
        float rP = rr * Qq;              // 1/(di*df)
        float rQ = rr * Pp;              // 1/(dc*dq)
        float ig = rP * df;              // 1/di
        float fg = rP * di;              // 1/df
        float rc = rQ * dq;              // 1/dc
        float og = rQ * dc;              // 1/dq
        float th = fmaf(-2.f, rc, 1.f);  // tanh(zc)
        c = fmaf(fg, c, ig * th);
        float acl = fminf(31.f, P2L2E * c);
        float dcl = 1.f + fexp2(acl);
        float tc  = fmaf(-2.f, frcp(dcl), 1.f);   // tanh(c)
        hval = og * tc;

        // publish h (split-bf16 packed) for next step
        uint32_t hb = bf16rne(hval);
        float lo = hval - __uint_as_float(hb << 16);
        hbuf[p ^ 1][col][4 * w + quad] = (hb << 16) | bf16rne(lo);

        xz = xzn;
        idn = idnn;
        __syncthreads();
        p ^= 1;
    }

    // ---- MLP head ----
    hfin[col][4 * w + quad] = hval;
    __syncthreads();

    int b = tid >> 5;        // 0..15
    int u = tid & 31;
    float y = b1[u];
#pragma unroll
    for (int k = 0; k < HDIM; ++k)
        y = fmaf(hfin[b][k], w1[k * HDIM + u], y);
    y = fmaxf(y, 0.f);
    float vv = y * w2[u];
#pragma unroll
    for (int off = 16; off >= 1; off >>= 1)
        vv += __shfl_xor(vv, off);   // stays within each 32-lane group
    if (u == 0) out[bb + b] = vv + b2[0];
}

extern "C" void kernel_launch(void* const* d_in, const int* in_sizes, int n_in,
                              void* d_out, int out_size, void* d_ws, size_t ws_size,
                              hipStream_t stream) {
    const int*   ids  = (const int*)d_in[0];
    const float* emb  = (const float*)d_in[1];
    const float* kern = (const float*)d_in[2];
    const float* rec  = (const float*)d_in[3];
    const float* w1   = (const float*)d_in[4];
    const float* b1   = (const float*)d_in[5];
    const float* w2   = (const float*)d_in[6];
    const float* b2   = (const float*)d_in[7];
    float* out = (float*)d_out;
    float* P2  = (float*)d_ws;   // 512 KB scratch

    precompute_P2_kernel<<<(HASH_BUCKETS * G4 + 255) / 256, 256, 0, stream>>>(
        emb, kern, P2);
    lstm_head_kernel<<<BATCH / 16, 512, 0, stream>>>(
        ids, P2, rec, w1, b1, w2, b2, out);
}